// Round 6
// baseline (93986.951 us; speedup 1.0000x reference)
//
#include <hip/hip_runtime.h>
#include <math.h>

#define DIMX 512
#define NHEADS 8
#define DHE 64
#define NB 266
#define FFD 2048
#define OUTD 32
#define BATCH 4
#define SEQ 8192
#define NTOK 32768
#define HALF 16384
#define NLAYER 6
#define HCH 64   // chunks per head (per half); 256 tokens per block
#define FPW 54   // features per wave: m = w*54 + k
#define KPS_STRIDE 20  // floats per feature row in kps LDS (16-B aligned, conflict-spread)

#define DN_F 0.35355339059327373f
#define EPS_F 1e-4f

typedef unsigned short ushort_t;
typedef __attribute__((ext_vector_type(8))) short short8;
typedef __attribute__((ext_vector_type(4))) float floatx4;

__device__ __forceinline__ float gelu_f(float x) {
    float x3 = x * x * x;
    return 0.5f * x * (1.0f + tanhf(0.7978845608028654f * (x + 0.044715f * x3)));
}

__device__ __forceinline__ ushort_t f2bf(float f) {
    unsigned int u = __float_as_uint(f);
    unsigned int r = (u + 0x7fffu + ((u >> 16) & 1u)) >> 16;
    return (ushort_t)r;
}
__device__ __forceinline__ float bfu(ushort_t u) { return __uint_as_float(((unsigned int)u) << 16); }
__device__ __forceinline__ float bflo(unsigned int u) { return __uint_as_float(u << 16); }
__device__ __forceinline__ float bfhi(unsigned int u) { return __uint_as_float(u & 0xffff0000u); }

__device__ __forceinline__ unsigned int fkey(float f) {
    unsigned int u = __float_as_uint(f);
    return (u & 0x80000000u) ? ~u : (u | 0x80000000u);
}
__device__ __forceinline__ float funkey(unsigned int k) {
    unsigned int u = (k & 0x80000000u) ? (k & 0x7fffffffu) : ~k;
    return __uint_as_float(u);
}

// dot of one bf16 row (64 elems, LDS or global) against fp32 proj row in pr[16]
__device__ __forceinline__ float dot64bf(const ushort_t* kr, const float4* pr) {
    const uint4* k4 = (const uint4*)kr;
    float acc = 0.f;
#pragma unroll
    for (int j = 0; j < 8; j++) {
        uint4 u = k4[j];
        float4 p0 = pr[2 * j], p1 = pr[2 * j + 1];
        acc += bflo(u.x) * p0.x; acc += bfhi(u.x) * p0.y;
        acc += bflo(u.y) * p0.z; acc += bfhi(u.y) * p0.w;
        acc += bflo(u.z) * p1.x; acc += bfhi(u.z) * p1.y;
        acc += bflo(u.w) * p1.z; acc += bfhi(u.w) * p1.w;
    }
    return acc;
}

__global__ __launch_bounds__(256) void zero_kernel(float* __restrict__ p, int n) {
    int i = blockIdx.x * 256 + threadIdx.x;
    if (i < n) p[i] = 0.f;
}

// ---------------- LayerNorm -> bf16 ----------------
__global__ __launch_bounds__(256) void ln_bf16_kernel(const float* __restrict__ x,
                                                      const float* __restrict__ g,
                                                      const float* __restrict__ b,
                                                      ushort_t* __restrict__ out) {
    int row = blockIdx.x * 4 + (threadIdx.x >> 6);
    int lane = threadIdx.x & 63;
    const float4* xr = (const float4*)(x + (size_t)row * DIMX);
    float4 v0 = xr[lane];
    float4 v1 = xr[lane + 64];
    float sum = v0.x + v0.y + v0.z + v0.w + v1.x + v1.y + v1.z + v1.w;
#pragma unroll
    for (int off = 32; off; off >>= 1) sum += __shfl_xor(sum, off);
    float mu = sum * (1.0f / 512.0f);
    float var = (v0.x - mu) * (v0.x - mu) + (v0.y - mu) * (v0.y - mu) +
                (v0.z - mu) * (v0.z - mu) + (v0.w - mu) * (v0.w - mu) +
                (v1.x - mu) * (v1.x - mu) + (v1.y - mu) * (v1.y - mu) +
                (v1.z - mu) * (v1.z - mu) + (v1.w - mu) * (v1.w - mu);
#pragma unroll
    for (int off = 32; off; off >>= 1) var += __shfl_xor(var, off);
    float rstd = rsqrtf(var * (1.0f / 512.0f) + 1e-5f);
    const float4* g4 = (const float4*)g;
    const float4* b4 = (const float4*)b;
    ushort_t* orow = out + (size_t)row * DIMX;
    float4 gg = g4[lane], bb = b4[lane];
    ushort4 o;
    o.x = f2bf((v0.x - mu) * rstd * gg.x + bb.x);
    o.y = f2bf((v0.y - mu) * rstd * gg.y + bb.y);
    o.z = f2bf((v0.z - mu) * rstd * gg.z + bb.z);
    o.w = f2bf((v0.w - mu) * rstd * gg.w + bb.w);
    *(ushort4*)(orow + lane * 4) = o;
    gg = g4[lane + 64]; bb = b4[lane + 64];
    o.x = f2bf((v1.x - mu) * rstd * gg.x + bb.x);
    o.y = f2bf((v1.y - mu) * rstd * gg.y + bb.y);
    o.z = f2bf((v1.z - mu) * rstd * gg.z + bb.z);
    o.w = f2bf((v1.w - mu) * rstd * gg.w + bb.w);
    *(ushort4*)(orow + 256 + lane * 4) = o;
}

// ---------------- weight transpose-convert ----------------
__global__ __launch_bounds__(256) void wconv_kernel(const float* __restrict__ W,
                                                    ushort_t* __restrict__ Wt,
                                                    int K, int N) {
    __shared__ float tile[32][33];
    int bx = blockIdx.x * 32;
    int by = blockIdx.y * 32;
    int tx = threadIdx.x & 31, ty = threadIdx.x >> 5;
#pragma unroll
    for (int r = 0; r < 4; r++)
        tile[ty + r * 8][tx] = W[(size_t)(by + ty + r * 8) * N + bx + tx];
    __syncthreads();
#pragma unroll
    for (int r = 0; r < 4; r++)
        Wt[(size_t)(bx + ty + r * 8) * K + by + tx] = f2bf(tile[tx][ty + r * 8]);
}

__device__ __forceinline__ void gl_lds16(const void* g, void* l) {
    __builtin_amdgcn_global_load_lds(
        (const __attribute__((address_space(1))) unsigned int*)g,
        (__attribute__((address_space(3))) unsigned int*)l, 16, 0, 0);
}

// ---------------- bf16 MFMA GEMM ----------------
template <int EPI>
__global__ __launch_bounds__(256) void gemm_mfma(const ushort_t* __restrict__ A,
                                                 const ushort_t* __restrict__ Bt,
                                                 const float* __restrict__ bias,
                                                 float* __restrict__ C,
                                                 ushort_t* __restrict__ Cb,
                                                 int M, int N, int K) {
    __shared__ ushort_t As[128 * 32];
    __shared__ ushort_t Bs[128 * 32];
    int t = threadIdx.x;
    int wave = t >> 6, lane = t & 63;
    int wm = wave >> 1, wn = wave & 1;
    int m0 = blockIdx.x * 128, n0 = blockIdx.y * 128;
    int q = lane >> 4, ml = lane & 15;

    floatx4 acc[4][4];
#pragma unroll
    for (int i = 0; i < 4; i++)
#pragma unroll
        for (int j = 0; j < 4; j++) acc[i][j] = (floatx4)(0.f);

    int srow = (lane >> 2);
    int scol = (lane & 3) * 8;
    const ushort_t* Ag = A + (size_t)(m0 + wave * 32 + srow) * K + scol;
    const ushort_t* Bg = Bt + (size_t)(n0 + wave * 32 + srow) * K + scol;
    ushort_t* AsW = &As[(wave * 32) * 32];
    ushort_t* BsW = &Bs[(wave * 32) * 32];

    for (int k0 = 0; k0 < K; k0 += 32) {
        gl_lds16(Ag + k0, AsW);
        gl_lds16(Ag + k0 + (size_t)16 * K, AsW + 16 * 32);
        gl_lds16(Bg + k0, BsW);
        gl_lds16(Bg + k0 + (size_t)16 * K, BsW + 16 * 32);
        __syncthreads();
        short8 a[4], b[4];
#pragma unroll
        for (int i = 0; i < 4; i++)
            a[i] = *(const short8*)&As[(wm * 64 + i * 16 + ml) * 32 + q * 8];
#pragma unroll
        for (int j = 0; j < 4; j++)
            b[j] = *(const short8*)&Bs[(wn * 64 + j * 16 + ml) * 32 + q * 8];
#pragma unroll
        for (int i = 0; i < 4; i++)
#pragma unroll
            for (int j = 0; j < 4; j++)
                acc[i][j] = __builtin_amdgcn_mfma_f32_16x16x32_bf16(a[i], b[j], acc[i][j], 0, 0, 0);
        __syncthreads();
    }

#pragma unroll
    for (int i = 0; i < 4; i++) {
#pragma unroll
        for (int r = 0; r < 4; r++) {
            size_t row = (size_t)m0 + wm * 64 + i * 16 + q * 4 + r;
#pragma unroll
            for (int j = 0; j < 4; j++) {
                int col = n0 + wn * 64 + j * 16 + ml;
                float v = acc[i][j][r];
                if (EPI == 0) {
                    C[row * N + col] = v;
                } else if (EPI == 1) {
                    C[row * N + col] += v + bias[col];
                } else if (EPI == 2) {
                    Cb[row * N + col] = f2bf(gelu_f(v + bias[col]));
                } else {
                    Cb[row * N + col] = f2bf(v);
                }
            }
        }
    }
}

// ---------------- fp32 VALU GEMM (final fc, N=32) ----------------
template <int DOACC, int DOGELU>
__global__ __launch_bounds__(256) void gemm_kernel(const float* __restrict__ A,
                                                   const float* __restrict__ B,
                                                   const float* __restrict__ bias,
                                                   float* __restrict__ C,
                                                   int M, int N, int K) {
    __shared__ float As[16][132];
    __shared__ float Bs[16][132];
    int t = threadIdx.x;
    int tx = t & 15, ty = t >> 4;
    int m0 = blockIdx.x * 128;
    int n0 = blockIdx.y * 128;
    float c[8][8];
#pragma unroll
    for (int i = 0; i < 8; i++)
#pragma unroll
        for (int j = 0; j < 8; j++) c[i][j] = 0.f;
    int am = t >> 1;
    int ak = (t & 1) * 8;
    const float* Aptr = A + (size_t)(m0 + am) * K + ak;
    int bn = (t & 15) * 8;
    int bk = t >> 4;
    bool bvalid = (n0 + bn) < N;
    const float* Bptr = B + (size_t)bk * N + n0 + bn;
    for (int k0 = 0; k0 < K; k0 += 16) {
        float4 a0 = *(const float4*)(Aptr + k0);
        float4 a1 = *(const float4*)(Aptr + k0 + 4);
        As[ak + 0][am] = a0.x; As[ak + 1][am] = a0.y;
        As[ak + 2][am] = a0.z; As[ak + 3][am] = a0.w;
        As[ak + 4][am] = a1.x; As[ak + 5][am] = a1.y;
        As[ak + 6][am] = a1.z; As[ak + 7][am] = a1.w;
        float4 b0 = make_float4(0.f, 0.f, 0.f, 0.f);
        float4 b1v = make_float4(0.f, 0.f, 0.f, 0.f);
        if (bvalid) {
            const float* bp = Bptr + (size_t)k0 * N;
            b0 = *(const float4*)bp;
            b1v = *(const float4*)(bp + 4);
        }
        *(float4*)&Bs[bk][bn] = b0;
        *(float4*)&Bs[bk][bn + 4] = b1v;
        __syncthreads();
#pragma unroll
        for (int kk = 0; kk < 16; kk++) {
            float4 av0 = *(const float4*)&As[kk][ty * 4];
            float4 av1 = *(const float4*)&As[kk][64 + ty * 4];
            float4 bv0 = *(const float4*)&Bs[kk][tx * 4];
            float4 bv1 = *(const float4*)&Bs[kk][64 + tx * 4];
            float a_[8] = {av0.x, av0.y, av0.z, av0.w, av1.x, av1.y, av1.z, av1.w};
            float b_[8] = {bv0.x, bv0.y, bv0.z, bv0.w, bv1.x, bv1.y, bv1.z, bv1.w};
#pragma unroll
            for (int i = 0; i < 8; i++)
#pragma unroll
                for (int j = 0; j < 8; j++) c[i][j] += a_[i] * b_[j];
        }
        __syncthreads();
    }
#pragma unroll
    for (int ih = 0; ih < 2; ih++)
#pragma unroll
        for (int il = 0; il < 4; il++) {
            size_t row = (size_t)m0 + ih * 64 + ty * 4 + il;
#pragma unroll
            for (int jh = 0; jh < 2; jh++) {
                int colbase = n0 + jh * 64 + tx * 4;
                if (colbase < N) {
                    float* cp = C + row * N + colbase;
#pragma unroll
                    for (int jl = 0; jl < 4; jl++) {
                        float v = c[ih * 4 + il][jh * 4 + jl];
                        if (bias) v += bias[colbase + jl];
                        if (DOGELU) v = gelu_f(v);
                        if (DOACC) v += cp[jl];
                        cp[jl] = v;
                    }
                }
            }
        }
}

// ---------------- kmax: LDS-staged tiles of 16 contiguous rows ----------------
__global__ __launch_bounds__(320) void kmax_kernel(const ushort_t* __restrict__ Kf,
                                                   const float* __restrict__ proj,
                                                   unsigned int* __restrict__ kmaxkey,
                                                   int rows_per_block) {
    __shared__ __align__(16) ushort_t KtS[16 * 64];
    int tid = threadIdx.x;
    float4 pr[16];
    if (tid < NB) {
#pragma unroll
        for (int j = 0; j < 16; j++) pr[j] = ((const float4*)proj)[tid * 16 + j];
    }
    float lmax = -3.0e38f;
    size_t r0 = (size_t)blockIdx.x * rows_per_block;
    int ntiles = rows_per_block / 16;
    for (int g = 0; g < ntiles; g++) {
        if (tid < 128)
            *(uint4*)&KtS[tid * 8] = *(const uint4*)(Kf + (r0 + g * 16) * DHE + tid * 8);
        __syncthreads();
        if (tid < NB) {
#pragma unroll
            for (int r = 0; r < 16; r++)
                lmax = fmaxf(lmax, dot64bf(&KtS[r * 64], pr));
        }
        __syncthreads();
    }
    lmax *= DN_F;
#pragma unroll
    for (int off = 32; off; off >>= 1) lmax = fmaxf(lmax, __shfl_xor(lmax, off));
    __shared__ float wmax[5];
    if ((tid & 63) == 0) wmax[tid >> 6] = lmax;
    __syncthreads();
    if (tid == 0) {
        float bm = wmax[0];
        for (int w = 1; w < 5; w++) bm = fmaxf(bm, wmax[w]);
        atomicMax(kmaxkey, fkey(bm));
    }
}

// ------------- ctx: LDS-staged 16-token tiles -------------
__global__ __launch_bounds__(320) void ctx_kernel(const ushort_t* __restrict__ Kf,
                                                  const ushort_t* __restrict__ Vf,
                                                  const float* __restrict__ proj,
                                                  const unsigned int* __restrict__ kmaxkey,
                                                  float* __restrict__ CTX,
                                                  float* __restrict__ KS,
                                                  float* __restrict__ VS,
                                                  int base_b) {
    __shared__ __align__(16) ushort_t KtS[16 * 64];
    __shared__ __align__(16) ushort_t VtS[16 * 64];
    __shared__ __align__(16) float kpsS[270 * KPS_STRIDE];
    __shared__ float e2S[16];
    int tid = threadIdx.x;
    int h = blockIdx.x / HCH, ch = blockIdx.x % HCH;
    int bh = (base_b + (ch >> 5)) * NHEADS + h;
    int w = tid >> 6, d = tid & 63;
    float4 pr[16];
    if (tid < NB) {
#pragma unroll
        for (int j = 0; j < 16; j++) pr[j] = ((const float4*)proj)[tid * 16 + j];
    }
    float mx = funkey(*kmaxkey);
    float cacc[FPW];
#pragma unroll
    for (int k = 0; k < FPW; k++) cacc[k] = 0.f;
    float ksum_r = 0.f, vsum_r = 0.f;
    int tokbase = ch * 256;
    for (int g = 0; g < 16; g++) {
        int tok0 = tokbase + g * 16;
        if (tid < 128) {
            int r = tid >> 3, c = (tid & 7) * 8;
            *(uint4*)&KtS[r * 64 + c] = *(const uint4*)(Kf + (size_t)(tok0 + r) * DIMX + h * DHE + c);
        } else if (tid < 256) {
            int r = (tid - 128) >> 3, c = ((tid - 128) & 7) * 8;
            *(uint4*)&VtS[r * 64 + c] = *(const uint4*)(Vf + (size_t)(tok0 + r) * DIMX + h * DHE + c);
        }
        __syncthreads();  // b1: tiles ready
        if (tid < 256) {
            int tt = tid >> 4, dd = (tid & 15) * 4;
            float s0 = bfu(KtS[tt * 64 + dd]), s1 = bfu(KtS[tt * 64 + dd + 1]);
            float s2 = bfu(KtS[tt * 64 + dd + 2]), s3 = bfu(KtS[tt * 64 + dd + 3]);
            float ssp = s0 * s0 + s1 * s1 + s2 * s2 + s3 * s3;
#pragma unroll
            for (int off = 8; off; off >>= 1) ssp += __shfl_xor(ssp, off);
            if ((tid & 15) == 0) e2S[tt] = __expf(-ssp * 0.0625f);
        }
        float xp[16];
        if (tid < NB) {
#pragma unroll
            for (int t = 0; t < 16; t++) xp[t] = dot64bf(&KtS[t * 64], pr);
        }
        __syncthreads();  // b2: e2S ready
        if (tid < NB) {
            float4 kq[4];
#pragma unroll
            for (int t4 = 0; t4 < 4; t4++) {
                float e0 = e2S[t4 * 4 + 0], e1 = e2S[t4 * 4 + 1];
                float e2 = e2S[t4 * 4 + 2], e3 = e2S[t4 * 4 + 3];
                float k0 = __expf(xp[t4 * 4 + 0] * DN_F - mx) * e0;
                float k1 = __expf(xp[t4 * 4 + 1] * DN_F - mx) * e1;
                float k2 = __expf(xp[t4 * 4 + 2] * DN_F - mx) * e2;
                float k3 = __expf(xp[t4 * 4 + 3] * DN_F - mx) * e3;
                ksum_r += k0 + k1 + k2 + k3;
                kq[t4] = make_float4(k0, k1, k2, k3);
            }
#pragma unroll
            for (int t4 = 0; t4 < 4; t4++)
                *(float4*)&kpsS[tid * KPS_STRIDE + t4 * 4] = kq[t4];
        }
        if (w == 4) {
#pragma unroll
            for (int t = 0; t < 16; t++) vsum_r += bfu(VtS[t * 64 + d]);
        }
        __syncthreads();  // b3: kps ready
        float vv[16];
#pragma unroll
        for (int t = 0; t < 16; t++) vv[t] = bfu(VtS[t * 64 + d]);
#pragma unroll
        for (int k = 0; k < FPW; k++) {
            int m = w * FPW + k;
            if (m < NB) {
                const float* kp = &kpsS[m * KPS_STRIDE];
                float4 a = *(const float4*)(kp);
                float4 b = *(const float4*)(kp + 4);
                float4 c = *(const float4*)(kp + 8);
                float4 e = *(const float4*)(kp + 12);
                cacc[k] += a.x * vv[0] + a.y * vv[1] + a.z * vv[2] + a.w * vv[3] +
                           b.x * vv[4] + b.y * vv[5] + b.z * vv[6] + b.w * vv[7] +
                           c.x * vv[8] + c.y * vv[9] + c.z * vv[10] + c.w * vv[11] +
                           e.x * vv[12] + e.y * vv[13] + e.z * vv[14] + e.w * vv[15];
            }
        }
        __syncthreads();  // b4: before next tile overwrites
    }
    float* ctxp = CTX + (size_t)bh * (NB * DHE);
#pragma unroll
    for (int k = 0; k < FPW; k++) {
        int m = w * FPW + k;
        if (m < NB) atomicAdd(&ctxp[m * DHE + d], cacc[k]);
    }
    if (tid < NB) atomicAdd(&KS[(size_t)bh * NB + tid], ksum_r);
    if (w == 4) atomicAdd(&VS[(size_t)bh * DHE + d], vsum_r);
}

// ------------- o: LDS-staged 16-token tiles -------------
__global__ __launch_bounds__(320) void o_kernel(const ushort_t* __restrict__ Qf,
                                                const float* __restrict__ proj,
                                                const float* __restrict__ CTX,
                                                const float* __restrict__ KS,
                                                const float* __restrict__ VS,
                                                ushort_t* __restrict__ Of,
                                                int base_b) {
    __shared__ __align__(16) ushort_t QtS[16 * 64];
    __shared__ __align__(16) float qpsS[270 * KPS_STRIDE];
    __shared__ __align__(16) float opartS[5 * 64 * KPS_STRIDE];
    __shared__ float e2S[16];
    __shared__ float wmaxS[5][16];
    __shared__ float dpS[5][16];
    __shared__ float ctS[DHE];
    __shared__ float kstS[5];
    int tid = threadIdx.x;
    int h = blockIdx.x / HCH, ch = blockIdx.x % HCH;
    int bh = (base_b + (ch >> 5)) * NHEADS + h;
    int w = tid >> 6, d = tid & 63;
    float4 pr[16];
    if (tid < NB) {
#pragma unroll
        for (int j = 0; j < 16; j++) pr[j] = ((const float4*)proj)[tid * 16 + j];
    }
    float vs_eps = EPS_F * VS[(size_t)bh * DHE + d];
    const float* ctxp = CTX + (size_t)bh * (NB * DHE);
    float creg[FPW];
    float csum = 0.f;
#pragma unroll
    for (int k = 0; k < FPW; k++) {
        int m = w * FPW + k;
        creg[k] = (m < NB) ? (ctxp[m * DHE + d] + vs_eps) : 0.f;
        csum += creg[k];
    }
    float ksr = (tid < NB) ? (KS[(size_t)bh * NB + tid] + EPS_F * 8192.0f) : 0.f;
    float kst = ksr;
#pragma unroll
    for (int off = 32; off; off >>= 1) kst += __shfl_xor(kst, off);
    if ((tid & 63) == 0) kstS[w] = kst;
    opartS[(w * 64 + d) * KPS_STRIDE] = csum;
    __syncthreads();
    float kstot = kstS[0] + kstS[1] + kstS[2] + kstS[3] + kstS[4];
    if (tid < DHE) {
        float s = 0.f;
#pragma unroll
        for (int ww = 0; ww < 5; ww++) s += opartS[(ww * 64 + tid) * KPS_STRIDE];
        ctS[tid] = s;
    }
    __syncthreads();
    int tokbase = ch * 256;
    for (int g = 0; g < 16; g++) {
        int tok0 = tokbase + g * 16;
        if (tid < 128) {
            int r = tid >> 3, c = (tid & 7) * 8;
            *(uint4*)&QtS[r * 64 + c] = *(const uint4*)(Qf + (size_t)(tok0 + r) * DIMX + h * DHE + c);
        }
        __syncthreads();  // b1: Q tile ready
        if (tid < 256) {
            int tt = tid >> 4, dd = (tid & 15) * 4;
            float s0 = bfu(QtS[tt * 64 + dd]), s1 = bfu(QtS[tt * 64 + dd + 1]);
            float s2 = bfu(QtS[tt * 64 + dd + 2]), s3 = bfu(QtS[tt * 64 + dd + 3]);
            float ssp = s0 * s0 + s1 * s1 + s2 * s2 + s3 * s3;
#pragma unroll
            for (int off = 8; off; off >>= 1) ssp += __shfl_xor(ssp, off);
            if ((tid & 15) == 0) e2S[tt] = __expf(-ssp * 0.0625f);
        }
        float xq[16];
#pragma unroll
        for (int t = 0; t < 16; t++) xq[t] = -3.0e38f;
        if (tid < NB) {
#pragma unroll
            for (int t = 0; t < 16; t++) xq[t] = dot64bf(&QtS[t * 64], pr) * DN_F;
        }
        float mxv[16];
#pragma unroll
        for (int t = 0; t < 16; t++) {
            float m = xq[t];
#pragma unroll
            for (int off = 32; off; off >>= 1) m = fmaxf(m, __shfl_xor(m, off));
            mxv[t] = m;
        }
        if ((tid & 63) == 0) {
#pragma unroll
            for (int t = 0; t < 16; t++) wmaxS[w][t] = mxv[t];
        }
        __syncthreads();  // b2: maxes + e2S ready
        float dp[16];
        if (tid < NB) {
#pragma unroll
            for (int t4 = 0; t4 < 4; t4++) {
                float4 q;
                float r0 = fmaxf(fmaxf(fmaxf(wmaxS[0][t4 * 4 + 0], wmaxS[1][t4 * 4 + 0]),
                                       fmaxf(wmaxS[2][t4 * 4 + 0], wmaxS[3][t4 * 4 + 0])),
                                 wmaxS[4][t4 * 4 + 0]);
                float r1 = fmaxf(fmaxf(fmaxf(wmaxS[0][t4 * 4 + 1], wmaxS[1][t4 * 4 + 1]),
                                       fmaxf(wmaxS[2][t4 * 4 + 1], wmaxS[3][t4 * 4 + 1])),
                                 wmaxS[4][t4 * 4 + 1]);
                float r2 = fmaxf(fmaxf(fmaxf(wmaxS[0][t4 * 4 + 2], wmaxS[1][t4 * 4 + 2]),
                                       fmaxf(wmaxS[2][t4 * 4 + 2], wmaxS[3][t4 * 4 + 2])),
                                 wmaxS[4][t4 * 4 + 2]);
                float r3 = fmaxf(fmaxf(fmaxf(wmaxS[0][t4 * 4 + 3], wmaxS[1][t4 * 4 + 3]),
                                       fmaxf(wmaxS[2][t4 * 4 + 3], wmaxS[3][t4 * 4 + 3])),
                                 wmaxS[4][t4 * 4 + 3]);
                q.x = __expf(xq[t4 * 4 + 0] - r0);
                q.y = __expf(xq[t4 * 4 + 1] - r1);
                q.z = __expf(xq[t4 * 4 + 2] - r2);
                q.w = __expf(xq[t4 * 4 + 3] - r3);
                *(float4*)&qpsS[tid * KPS_STRIDE + t4 * 4] = q;
                dp[t4 * 4 + 0] = q.x * ksr; dp[t4 * 4 + 1] = q.y * ksr;
                dp[t4 * 4 + 2] = q.z * ksr; dp[t4 * 4 + 3] = q.w * ksr;
            }
        } else {
#pragma unroll
            for (int t = 0; t < 16; t++) dp[t] = 0.f;
        }
#pragma unroll
        for (int t = 0; t < 16; t++) {
#pragma unroll
            for (int off = 32; off; off >>= 1) dp[t] += __shfl_xor(dp[t], off);
        }
        if ((tid & 63) == 0) {
#pragma unroll
            for (int t = 0; t < 16; t++) dpS[w][t] = dp[t];
        }
        __syncthreads();  // b3: qps + dp partials ready
        float at[16];
#pragma unroll
        for (int t = 0; t < 16; t++) at[t] = 0.f;
#pragma unroll
        for (int k = 0; k < FPW; k++) {
            int m = w * FPW + k;
            if (m < NB) {
                const float* qp = &qpsS[m * KPS_STRIDE];
                float4 a = *(const float4*)(qp);
                float4 b = *(const float4*)(qp + 4);
                float4 c = *(const float4*)(qp + 8);
                float4 e = *(const float4*)(qp + 12);
                float cv = creg[k];
                at[0] += a.x * cv; at[1] += a.y * cv; at[2] += a.z * cv; at[3] += a.w * cv;
                at[4] += b.x * cv; at[5] += b.y * cv; at[6] += b.z * cv; at[7] += b.w * cv;
                at[8] += c.x * cv; at[9] += c.y * cv; at[10] += c.z * cv; at[11] += c.w * cv;
                at[12] += e.x * cv; at[13] += e.y * cv; at[14] += e.z * cv; at[15] += e.w * cv;
            }
        }
        float* op = &opartS[(w * 64 + d) * KPS_STRIDE];
#pragma unroll
        for (int t4 = 0; t4 < 4; t4++)
            *(float4*)(op + t4 * 4) = make_float4(at[t4 * 4], at[t4 * 4 + 1], at[t4 * 4 + 2], at[t4 * 4 + 3]);
        __syncthreads();  // b4: opart ready
#pragma unroll
        for (int p = 0; p < 4; p++) {
            int idx = p * 320 + tid;
            if (idx < 1024) {
                int t = idx >> 6, dd = idx & 63;
                float s = 0.f, B = 0.f;
#pragma unroll
                for (int ww = 0; ww < 5; ww++) {
                    s += opartS[(ww * 64 + dd) * KPS_STRIDE + t];
                    B += dpS[ww][t];
                }
                float e2q = e2S[t];
                float num = e2q * s + EPS_F * ctS[dd];
                float den = e2q * B + EPS_F * kstot;
                Of[(size_t)(tok0 + t) * DIMX + h * DHE + dd] = f2bf(num / den);
            }
        }
        __syncthreads();  // b5: outputs read; LDS free for next tile
    }
}

extern "C" void kernel_launch(void* const* d_in, const int* in_sizes, int n_in,
                              void* d_out, int out_size, void* d_ws, size_t ws_size,
                              hipStream_t stream) {
    (void)in_sizes; (void)n_in; (void)out_size; (void)ws_size;
    const float* src  = (const float*)d_in[0];
    const float* proj = (const float*)d_in[1];
    const float* ln1g = (const float*)d_in[2];
    const float* ln1b = (const float*)d_in[3];
    const float* Wq   = (const float*)d_in[4];
    const float* Wk   = (const float*)d_in[5];
    const float* Wv   = (const float*)d_in[6];
    const float* Wo   = (const float*)d_in[7];
    const float* bo   = (const float*)d_in[8];
    const float* ln2g = (const float*)d_in[9];
    const float* ln2b = (const float*)d_in[10];
    const float* W1   = (const float*)d_in[11];
    const float* b1   = (const float*)d_in[12];
    const float* W2   = (const float*)d_in[13];
    const float* b2   = (const float*)d_in[14];
    const float* fcw  = (const float*)d_in[15];
    const float* fcb  = (const float*)d_in[16];
    float* out = (float*)d_out;

    const size_t TD = (size_t)NTOK * DIMX;
    const size_t HD = (size_t)HALF * DIMX;
    const size_t SD = (size_t)SEQ * DIMX;
    float* X      = (float*)d_ws;
    ushort_t* H   = (ushort_t*)(X + TD);
    ushort_t* Pb  = H + TD;
    ushort_t* Rb  = Pb + HD;
    float* CTXb   = (float*)(Rb + HD);
    float* KSb    = CTXb + 32 * NB * DHE;
    float* VSb    = KSb + 32 * NB;
    unsigned int* KMAX = (unsigned int*)(VSb + 32 * DHE);
    ushort_t* Wqt = (ushort_t*)(KMAX + 4);
    ushort_t* Wkt = Wqt + DIMX * DIMX;
    ushort_t* Wvt = Wkt + DIMX * DIMX;
    ushort_t* Wot = Wvt + DIMX * DIMX;
    ushort_t* W1t = Wot + DIMX * DIMX;
    ushort_t* W2t = W1t + (size_t)DIMX * FFD;
    const int NZ = 32 * NB * DHE + 32 * NB + 32 * DHE + 4;

    hipMemcpyAsync(X, src, sizeof(float) * TD, hipMemcpyDeviceToDevice, stream);

    dim3 gH(HALF / 128, DIMX / 128);
    dim3 gF1(SEQ / 128, FFD / 128);
    dim3 gF2(SEQ / 128, DIMX / 128);
    for (int L = 0; L < NLAYER; L++) {
        const float* pj = proj + (size_t)L * NB * DHE;
        wconv_kernel<<<dim3(16, 16), 256, 0, stream>>>(Wq + (size_t)L * DIMX * DIMX, Wqt, DIMX, DIMX);
        wconv_kernel<<<dim3(16, 16), 256, 0, stream>>>(Wk + (size_t)L * DIMX * DIMX, Wkt, DIMX, DIMX);
        wconv_kernel<<<dim3(16, 16), 256, 0, stream>>>(Wv + (size_t)L * DIMX * DIMX, Wvt, DIMX, DIMX);
        wconv_kernel<<<dim3(16, 16), 256, 0, stream>>>(Wo + (size_t)L * DIMX * DIMX, Wot, DIMX, DIMX);
        wconv_kernel<<<dim3(64, 16), 256, 0, stream>>>(W1 + (size_t)L * DIMX * FFD, W1t, DIMX, FFD);
        wconv_kernel<<<dim3(16, 64), 256, 0, stream>>>(W2 + (size_t)L * FFD * DIMX, W2t, FFD, DIMX);
        zero_kernel<<<(NZ + 255) / 256, 256, 0, stream>>>(CTXb, NZ);
        ln_bf16_kernel<<<NTOK / 4, 256, 0, stream>>>(X, ln1g + L * DIMX, ln1b + L * DIMX, H);
        for (int half = 0; half < 2; half++) {
            gemm_mfma<3><<<gH, 256, 0, stream>>>(H + half * HD, Wkt, nullptr, nullptr, Pb, HALF, DIMX, DIMX);
            kmax_kernel<<<512, 320, 0, stream>>>(Pb, pj, KMAX, (HALF * NHEADS) / 512);
        }
        for (int half = 0; half < 2; half++) {
            const ushort_t* Hh = H + half * HD;
            gemm_mfma<3><<<gH, 256, 0, stream>>>(Hh, Wkt, nullptr, nullptr, Pb, HALF, DIMX, DIMX);
            gemm_mfma<3><<<gH, 256, 0, stream>>>(Hh, Wvt, nullptr, nullptr, Rb, HALF, DIMX, DIMX);
            ctx_kernel<<<NHEADS * HCH, 320, 0, stream>>>(Pb, Rb, pj, KMAX, CTXb, KSb, VSb, half * 2);
            gemm_mfma<3><<<gH, 256, 0, stream>>>(Hh, Wqt, nullptr, nullptr, Pb, HALF, DIMX, DIMX);
            o_kernel<<<NHEADS * HCH, 320, 0, stream>>>(Pb, pj, CTXb, KSb, VSb, Rb, half * 2);
            gemm_mfma<1><<<gH, 256, 0, stream>>>(Rb, Wot, bo + L * DIMX, X + half * HD, nullptr, HALF, DIMX, DIMX);
        }
        ln_bf16_kernel<<<NTOK / 4, 256, 0, stream>>>(X, ln2g + L * DIMX, ln2b + L * DIMX, H);
        for (int b = 0; b < BATCH; b++) {
            gemm_mfma<2><<<gF1, 256, 0, stream>>>(H + (size_t)b * SD, W1t, b1 + L * FFD, nullptr, Pb, SEQ, FFD, DIMX);
            gemm_mfma<1><<<gF2, 256, 0, stream>>>(Pb, W2t, b2 + L * DIMX, X + (size_t)b * SD, nullptr, SEQ, DIMX, FFD);
        }
    }
    gemm_kernel<0, 0><<<dim3(NTOK / 128, 1), 256, 0, stream>>>(X, fcw, fcb, out, NTOK, OUTD, DIMX);
}